// Round 16
// baseline (131.835 us; speedup 1.0000x reference)
//
#include <hip/hip_runtime.h>
#include <math.h>
#include <type_traits>

constexpr int BATCH = 16;

// ---------------------------------------------------------------------------
// Round 16: z-paired conv1 phase A. Consecutive zo share 3/5 input planes
// (stride 2), so one thread computes a 2(z) x 2(x) output tile from 7 plane
// loads instead of 10 (0.7x L2 traffic + 0.7x pq work). Phase A has no
// acc[24], so the cost is only a second z[3][2] (12 regs). Static 7-plane
// unroll with sched_barrier(0) per plane (register discipline, rounds 3-8).
//
// Workspace (floats):
//   A0 [16][20][33][33][36] : 12,545,280  (rows padded ->36)
//   A1 [16][20][18][18][20] :  2,073,600  (rows padded ->20)
//   S  [16][60][2] (pad)    :      2,048
//   Z1 [16][60][5832]       :  5,598,720  (full; half/quarter tiers smaller)
// ---------------------------------------------------------------------------

__host__ __device__ constexpr int QI(int q) {  // q = ay^2+ax^2 in {0,1,2,4,5,8}
  return q == 0 ? 0 : q == 1 ? 1 : q == 2 ? 2 : q == 4 ? 3 : q == 5 ? 4 : 5;
}

// Shared per-block radial-basis synthesis.
__device__ __forceinline__ void synth_basis(float* lbv, float* lnrm, int t) {
  if (t < 40) {
    const int gc = t >> 2, j = t & 3;
    const float R2C[10] = {0.f, 1.f, 2.f, 3.f, 4.f, 5.f, 6.f, 8.f, 9.f, 12.f};
    float raw = 0.f;
    if (j < 3) {
      const float d = (sqrtf(R2C[gc]) - (float)j) * (1.0f / 0.6f);
      raw = expf(-0.5f * d * d);
    }
    lbv[t] = raw;
  }
  __syncthreads();
  if (t < 3) {
    const float MULT[10] = {1.f, 6.f, 12.f, 8.f, 6.f, 24.f, 24.f, 12.f, 24.f, 8.f};
    float ssum = 0.f;
    for (int gc = 0; gc < 10; ++gc) {
      const float v = lbv[gc * 4 + t];
      ssum += MULT[gc] * v * v;
    }
    lnrm[t] = rsqrtf(ssum);
  }
  __syncthreads();
  if (t < 40) lbv[t] = ((t & 3) < 3) ? lbv[t] * lnrm[t & 3] : 0.f;
  __syncthreads();
}

// Radial tap-sum core for one strip (2 x-voxels) of one input channel.
template <int DIN, int DOUT, int IRS>
__device__ __forceinline__ void radial_z(const float* __restrict__ ipc,
                                         const float* __restrict__ lbv,
                                         int zo, int yo, int xo0,
                                         const bool* xok, const int* yoff,
                                         const bool* yok, int offA, int offB,
                                         float (&z)[3][2]) {
#pragma unroll
  for (int j = 0; j < 3; ++j) { z[j][0] = 0.f; z[j][1] = 0.f; }

  auto plane = [&](auto azc_c, int kz) {
    constexpr int AZC = decltype(azc_c)::value;
    constexpr int GM[3][6] = {
        {0, 1, 2, 4, 5, 7}, {1, 2, 3, 5, 6, 8}, {4, 5, 6, 7, 8, 9}};
    constexpr int A2T[5] = {4, 1, 0, 1, 4};
    const int zi = 2 * zo - 3 + kz;
    const bool zok = (unsigned)zi < (unsigned)DIN;
    const float* pl = ipc + (size_t)min(max(zi, 0), DIN - 1) * (DIN * IRS);
    float4 pa[5], pb[5];
#pragma unroll
    for (int ky = 0; ky < 5; ++ky) {
      const float* row = pl + yoff[ky];
      pa[ky] = *(const float4*)(row + offA);
      pb[ky] = *(const float4*)(row + offB);
    }
    float pq[6][2];
#pragma unroll
    for (int qi = 0; qi < 6; ++qi) { pq[qi][0] = 0.f; pq[qi][1] = 0.f; }
#pragma unroll
    for (int ky = 0; ky < 5; ++ky) {
      float v[7] = {pa[ky].y, pa[ky].z, pa[ky].w, pb[ky].x, pb[ky].y, pb[ky].z, pb[ky].w};
      const bool yz = zok && yok[ky];
#pragma unroll
      for (int p = 0; p < 7; ++p) v[p] = (yz && xok[p]) ? v[p] : 0.f;
#pragma unroll
      for (int kx = 0; kx < 5; ++kx) {
        pq[QI(A2T[ky] + A2T[kx])][0] += v[kx];
        pq[QI(A2T[ky] + A2T[kx])][1] += v[2 + kx];
      }
    }
#pragma unroll
    for (int qi = 0; qi < 6; ++qi) {
      const float4 bv4 = *(const float4*)&lbv[GM[AZC][qi] * 4];
#pragma unroll
      for (int n = 0; n < 2; ++n) {
        z[0][n] = fmaf(bv4.x, pq[qi][n], z[0][n]);
        z[1][n] = fmaf(bv4.y, pq[qi][n], z[1][n]);
        z[2][n] = fmaf(bv4.z, pq[qi][n], z[2][n]);
      }
    }
  };

  plane(std::integral_constant<int, 0>{}, 2);
#pragma unroll 1
  for (int rep = 0; rep < 2; ++rep) plane(std::integral_constant<int, 1>{}, 1 + 2 * rep);
#pragma unroll 1
  for (int rep = 0; rep < 2; ++rep) plane(std::integral_constant<int, 2>{}, 4 * rep);
}

// conv0 fused: ICT=1, tap-sum -> z[3][2] -> 23x3 mix + gate in epilogue.
__global__ __launch_bounds__(256)
void conv0_kernel(const float* __restrict__ in, const float* __restrict__ W0,
                  float* __restrict__ out) {
  constexpr int DIN = 64, DOUT = 33, IRS = 64, ORS = 36;
  constexpr int ISLAB = DIN * DIN * IRS;
  constexpr int OSLAB = DOUT * DOUT * ORS;
  constexpr int XS = 17, SPI = DOUT * DOUT * XS, NB = (SPI + 255) / 256;

  __shared__ __align__(16) float lbv[40];
  __shared__ float lnrm[4];
  __shared__ __align__(16) float lw[3 * 24];

  const int bid = blockIdx.x;
  const int xcd = bid & 7;
  int slot = bid >> 3;
  const int chunk = slot % NB; slot /= NB;
  const int b = xcd + 8 * slot;
  const int t = threadIdx.x;

  synth_basis(lbv, lnrm, t);
  if (t < 72) {
    const int oc = t % 24, j = t / 24;
    lw[t] = (oc < 23) ? W0[oc * 3 + j] : 0.f;
  }
  __syncthreads();

  const int s = chunk * 256 + t;
  const bool active = s < SPI;
  const int si = active ? s : 0;
  const int zo = si / (DOUT * XS);
  const int yo = (si / XS) % DOUT;
  const int xo0 = (si % XS) * 2;

  const float* __restrict__ ipc = in + (size_t)b * ISLAB;
  const int offA = max(2 * xo0 - 4, 0);
  const int offB = min(2 * xo0, IRS - 4);
  bool xok[7];
#pragma unroll
  for (int p = 0; p < 7; ++p) xok[p] = (unsigned)(2 * xo0 - 3 + p) < (unsigned)DIN;
  int yoff[5];
  bool yok[5];
#pragma unroll
  for (int ky = 0; ky < 5; ++ky) {
    const int yi = 2 * yo - 3 + ky;
    yok[ky] = (unsigned)yi < (unsigned)DIN;
    yoff[ky] = min(max(yi, 0), DIN - 1) * IRS;
  }

  float z[3][2];
  radial_z<DIN, DOUT, IRS>(ipc, lbv, zo, yo, xo0, xok, yoff, yok, offA, offB, z);

  if (!active) return;
  float* __restrict__ op = out + (size_t)b * 20 * OSLAB + (zo * DOUT + yo) * ORS + xo0;
#pragma unroll
  for (int n = 0; n < 2; ++n) {
    if (xo0 + n < DOUT) {
      float acc[24];
#pragma unroll
      for (int c4 = 0; c4 < 6; ++c4) {
        const float4 w0 = *(const float4*)&lw[0 * 24 + 4 * c4];
        const float4 w1 = *(const float4*)&lw[1 * 24 + 4 * c4];
        const float4 w2 = *(const float4*)&lw[2 * 24 + 4 * c4];
        acc[c4 * 4 + 0] = w0.x * z[0][n] + w1.x * z[1][n] + w2.x * z[2][n];
        acc[c4 * 4 + 1] = w0.y * z[0][n] + w1.y * z[1][n] + w2.y * z[2][n];
        acc[c4 * 4 + 2] = w0.z * z[0][n] + w1.z * z[1][n] + w2.z * z[2][n];
        acc[c4 * 4 + 3] = w0.w * z[0][n] + w1.w * z[1][n] + w2.w * z[2][n];
      }
      const float g0 = 1.f / (1.f + expf(-acc[20]));
      const float g1 = 1.f / (1.f + expf(-acc[21]));
      const float g2 = 1.f / (1.f + expf(-acc[22]));
#pragma unroll
      for (int c = 0; c < 5; ++c) op[(size_t)c * OSLAB + n] = fmaxf(acc[c], 0.f);
#pragma unroll
      for (int c = 0; c < 3; ++c) op[(size_t)(5 + c) * OSLAB + n] = acc[5 + c] * g0;
#pragma unroll
      for (int c = 0; c < 5; ++c) op[(size_t)(8 + c) * OSLAB + n] = acc[8 + c] * g1;
#pragma unroll
      for (int c = 0; c < 7; ++c) op[(size_t)(13 + c) * OSLAB + n] = acc[13 + c] * g2;
    }
  }
}

// conv1 phase A, z-paired: thread = 2(z) x 2(x) output voxels of one input
// channel; 7 shared input planes. Writes Z[brel][ic*3+j][vox], vox packed.
// DOUT must be even.
template <int ICT, int DIN, int DOUT, int IRS, int NBH>
__global__ __launch_bounds__(256)
void convA2_kernel(const float* __restrict__ in, float* __restrict__ outp, int bofs) {
  constexpr int ISLAB = DIN * DIN * IRS;
  constexpr int XS = DOUT / 2;
  constexpr int ZP = DOUT / 2;
  constexpr int SPI = ZP * DOUT * XS;
  constexpr int NB = (SPI + 255) / 256;
  constexpr int DOUT3 = DOUT * DOUT * DOUT;
  constexpr int XB = (NBH < 8) ? NBH : 8;

  __shared__ __align__(16) float lbv[40];
  __shared__ float lnrm[4];

  const int bid = blockIdx.x;
  const int xcd = bid & 7;
  int slot = bid >> 3;
  const int chunk = slot % NB; slot /= NB;
  const int ic = slot % ICT;   slot /= ICT;
  const int brel = (xcd % XB) + XB * slot;
  const int b = brel + bofs;
  const int t = threadIdx.x;

  synth_basis(lbv, lnrm, t);

  const int s = chunk * 256 + t;
  const bool active = s < SPI;
  const int si = active ? s : 0;
  const int zp = si / (DOUT * XS);
  const int yo = (si / XS) % DOUT;
  const int xo0 = (si % XS) * 2;

  const float* __restrict__ ipc = in + (size_t)(b * ICT + ic) * ISLAB;
  const int offA = max(2 * xo0 - 4, 0);
  const int offB = min(2 * xo0, IRS - 4);
  bool xok[7];
#pragma unroll
  for (int p = 0; p < 7; ++p) xok[p] = (unsigned)(2 * xo0 - 3 + p) < (unsigned)DIN;
  int yoff[5];
  bool yok[5];
#pragma unroll
  for (int ky = 0; ky < 5; ++ky) {
    const int yi = 2 * yo - 3 + ky;
    yok[ky] = (unsigned)yi < (unsigned)DIN;
    yoff[ky] = min(max(yi, 0), DIN - 1) * IRS;
  }

  float z0[3][2], z1[3][2];
#pragma unroll
  for (int j = 0; j < 3; ++j) {
    z0[j][0] = 0.f; z0[j][1] = 0.f;
    z1[j][0] = 0.f; z1[j][1] = 0.f;
  }

  auto fold = [&](auto azc_c, float (&zz)[3][2], const float (&pq)[6][2]) {
    constexpr int AZC = decltype(azc_c)::value;
    constexpr int GM[3][6] = {
        {0, 1, 2, 4, 5, 7}, {1, 2, 3, 5, 6, 8}, {4, 5, 6, 7, 8, 9}};
#pragma unroll
    for (int qi = 0; qi < 6; ++qi) {
      const float4 bv4 = *(const float4*)&lbv[GM[AZC][qi] * 4];
#pragma unroll
      for (int n = 0; n < 2; ++n) {
        zz[0][n] = fmaf(bv4.x, pq[qi][n], zz[0][n]);
        zz[1][n] = fmaf(bv4.y, pq[qi][n], zz[1][n]);
        zz[2][n] = fmaf(bv4.z, pq[qi][n], zz[2][n]);
      }
    }
  };

  auto planeP = [&](auto pc) {
    constexpr int P = decltype(pc)::value;
    constexpr int AZCmap[5] = {2, 1, 0, 1, 2};  // (kz-2)^2 -> class index
    const int zi = 4 * zp - 3 + P;
    const bool zok = (unsigned)zi < (unsigned)DIN;
    const float* pl = ipc + (size_t)min(max(zi, 0), DIN - 1) * (DIN * IRS);
    float4 pa[5], pb[5];
#pragma unroll
    for (int ky = 0; ky < 5; ++ky) {
      const float* row = pl + yoff[ky];
      pa[ky] = *(const float4*)(row + offA);
      pb[ky] = *(const float4*)(row + offB);
    }
    float pq[6][2];
#pragma unroll
    for (int qi = 0; qi < 6; ++qi) { pq[qi][0] = 0.f; pq[qi][1] = 0.f; }
#pragma unroll
    for (int ky = 0; ky < 5; ++ky) {
      constexpr int A2T[5] = {4, 1, 0, 1, 4};
      float v[7] = {pa[ky].y, pa[ky].z, pa[ky].w, pb[ky].x, pb[ky].y, pb[ky].z, pb[ky].w};
      const bool yz = zok && yok[ky];
#pragma unroll
      for (int p = 0; p < 7; ++p) v[p] = (yz && xok[p]) ? v[p] : 0.f;
#pragma unroll
      for (int kx = 0; kx < 5; ++kx) {
        pq[QI(A2T[ky] + A2T[kx])][0] += v[kx];
        pq[QI(A2T[ky] + A2T[kx])][1] += v[2 + kx];
      }
    }
    if constexpr (P <= 4) fold(std::integral_constant<int, AZCmap[P]>{}, z0, pq);
    if constexpr (P >= 2) fold(std::integral_constant<int, AZCmap[P - 2]>{}, z1, pq);
    __builtin_amdgcn_sched_barrier(0);
  };

  planeP(std::integral_constant<int, 0>{});
  planeP(std::integral_constant<int, 1>{});
  planeP(std::integral_constant<int, 2>{});
  planeP(std::integral_constant<int, 3>{});
  planeP(std::integral_constant<int, 4>{});
  planeP(std::integral_constant<int, 5>{});
  planeP(std::integral_constant<int, 6>{});

  if (!active) return;
  const int zo = 2 * zp;
  float* __restrict__ zpout = outp + ((size_t)(brel * ICT + ic) * 3) * DOUT3 +
                              ((size_t)zo * DOUT + yo) * DOUT + xo0;
#pragma unroll
  for (int j = 0; j < 3; ++j) {
    *(float2*)&zpout[(size_t)j * DOUT3] = make_float2(z0[j][0], z0[j][1]);
    *(float2*)&zpout[(size_t)j * DOUT3 + DOUT * DOUT] = make_float2(z1[j][0], z1[j][1]);
  }
}

// conv2 phase A: z per (ic, 2-voxel strip), block-reduced -> S[..][chunk].
template <int ICT, int DIN, int DOUT, int IRS, int NBH>
__global__ __launch_bounds__(256)
void convA_red_kernel(const float* __restrict__ in, float* __restrict__ outp, int bofs) {
  constexpr int ISLAB = DIN * DIN * IRS;
  constexpr int XS = (DOUT + 1) / 2;
  constexpr int SPI = DOUT * DOUT * XS;
  constexpr int NB = (SPI + 255) / 256;
  constexpr int XB = (NBH < 8) ? NBH : 8;
  static_assert(NB == 2, "S layout assumes 2 chunks");

  __shared__ __align__(16) float lbv[40];
  __shared__ float lnrm[4];
  __shared__ float red[4][3];

  const int bid = blockIdx.x;
  const int xcd = bid & 7;
  int slot = bid >> 3;
  const int chunk = slot % NB; slot /= NB;
  const int ic = slot % ICT;   slot /= ICT;
  const int brel = (xcd % XB) + XB * slot;
  const int b = brel + bofs;
  const int t = threadIdx.x;

  synth_basis(lbv, lnrm, t);

  const int s = chunk * 256 + t;
  const bool active = s < SPI;
  const int si = active ? s : 0;
  const int zo = si / (DOUT * XS);
  const int yo = (si / XS) % DOUT;
  const int xo0 = (si % XS) * 2;

  const float* __restrict__ ipc = in + (size_t)(b * ICT + ic) * ISLAB;
  const int offA = max(2 * xo0 - 4, 0);
  const int offB = min(2 * xo0, IRS - 4);
  bool xok[7];
#pragma unroll
  for (int p = 0; p < 7; ++p) xok[p] = (unsigned)(2 * xo0 - 3 + p) < (unsigned)DIN;
  int yoff[5];
  bool yok[5];
#pragma unroll
  for (int ky = 0; ky < 5; ++ky) {
    const int yi = 2 * yo - 3 + ky;
    yok[ky] = (unsigned)yi < (unsigned)DIN;
    yoff[ky] = min(max(yi, 0), DIN - 1) * IRS;
  }

  float z[3][2];
  radial_z<DIN, DOUT, IRS>(ipc, lbv, zo, yo, xo0, xok, yoff, yok, offA, offB, z);

  float v3[3];
#pragma unroll
  for (int j = 0; j < 3; ++j) v3[j] = active ? (z[j][0] + z[j][1]) : 0.f;
#pragma unroll
  for (int j = 0; j < 3; ++j) {
#pragma unroll
    for (int off = 32; off > 0; off >>= 1) v3[j] += __shfl_down(v3[j], off);
  }
  const int lane = t & 63, wv = t >> 6;
  if (lane == 0) {
#pragma unroll
    for (int j = 0; j < 3; ++j) red[wv][j] = v3[j];
  }
  __syncthreads();
  if (t < 3)
    outp[((size_t)(brel * ICT + ic) * 3 + t) * NB + chunk] =
        (red[0][t] + red[1][t]) + (red[2][t] + red[3][t]);
}

// Phase B: channel mix (23 out-ch from K z-features) + capsule gating.
template <int K, int DOUT, int ORS, int NBH>
__global__ __launch_bounds__(128)
void convB_kernel(const float* __restrict__ Z, const float* __restrict__ W,
                  float* __restrict__ out) {
  constexpr int ICT = K / 3;
  constexpr int DOUT3 = DOUT * DOUT * DOUT;
  constexpr int OSLAB = DOUT * DOUT * ORS;

  __shared__ __align__(16) float lw[K * 24];
  const int t = threadIdx.x;
  for (int i = t; i < K * 24; i += 128) {
    const int oc = i % 24, k = i / 24, icc = k / 3, jj = k % 3;
    lw[i] = (oc < 23) ? W[((size_t)oc * ICT + icc) * 3 + jj] : 0.f;
  }
  __syncthreads();

  const int gv = blockIdx.x * 128 + t;
  if (gv >= NBH * DOUT3) return;
  const int b = gv / DOUT3;
  const int vox = gv % DOUT3;

  float acc[24];
#pragma unroll
  for (int c = 0; c < 24; ++c) acc[c] = 0.f;

  const float* __restrict__ zp = Z + (size_t)b * K * DOUT3 + vox;
#pragma unroll 10
  for (int k = 0; k < K; ++k) {
    const float zv = zp[(size_t)k * DOUT3];
#pragma unroll
    for (int c4 = 0; c4 < 6; ++c4) {
      const float4 w4 = *(const float4*)&lw[k * 24 + 4 * c4];
      acc[c4 * 4 + 0] = fmaf(w4.x, zv, acc[c4 * 4 + 0]);
      acc[c4 * 4 + 1] = fmaf(w4.y, zv, acc[c4 * 4 + 1]);
      acc[c4 * 4 + 2] = fmaf(w4.z, zv, acc[c4 * 4 + 2]);
      acc[c4 * 4 + 3] = fmaf(w4.w, zv, acc[c4 * 4 + 3]);
    }
  }

  const int zz = vox / (DOUT * DOUT), yy = (vox / DOUT) % DOUT, xx = vox % DOUT;
  float* __restrict__ op = out + (size_t)b * 20 * OSLAB + (zz * DOUT + yy) * ORS + xx;
  const float g0 = 1.f / (1.f + expf(-acc[20]));
  const float g1 = 1.f / (1.f + expf(-acc[21]));
  const float g2 = 1.f / (1.f + expf(-acc[22]));
#pragma unroll
  for (int c = 0; c < 5; ++c) op[(size_t)c * OSLAB] = fmaxf(acc[c], 0.f);
#pragma unroll
  for (int c = 0; c < 3; ++c) op[(size_t)(5 + c) * OSLAB] = acc[5 + c] * g0;
#pragma unroll
  for (int c = 0; c < 5; ++c) op[(size_t)(8 + c) * OSLAB] = acc[8 + c] * g1;
#pragma unroll
  for (int c = 0; c < 7; ++c) op[(size_t)(13 + c) * OSLAB] = acc[13 + c] * g2;
}

// conv2 channel-mix (commuted past AvgSpacial) + fc1(relu) + fc2, one block.
__global__ __launch_bounds__(256)
void fc_kernel(const float* __restrict__ S, const float* __restrict__ W2,
               const float* __restrict__ fc1w, const float* __restrict__ fc1b,
               const float* __restrict__ fc2w, const float* __restrict__ fc2b,
               float* __restrict__ out) {
  const int t = threadIdx.x;
  __shared__ float SB[960];
  __shared__ float xs[320];
  __shared__ float hh[800];
  for (int i = t; i < 960; i += 256)
    SB[i] = S[(size_t)i * 2] + S[(size_t)i * 2 + 1];
  __syncthreads();
  for (int i = t; i < 320; i += 256) {
    const int b = i / 20, oc = i % 20;
    float s = 0.f;
    for (int k = 0; k < 60; ++k) s += W2[oc * 60 + k] * SB[b * 60 + k];
    xs[i] = s * (1.0f / 1000.0f);
  }
  __syncthreads();
  for (int i = t; i < 800; i += 256) {
    const int b = i / 50, j = i % 50;
    float s = fc1b[j];
    for (int c = 0; c < 20; ++c) s += xs[b * 20 + c] * fc1w[j * 20 + c];
    hh[i] = fmaxf(s, 0.f);
  }
  __syncthreads();
  for (int i = t; i < 32; i += 256) {
    const int b = i / 2, k = i % 2;
    float s = fc2b[k];
    for (int j = 0; j < 50; ++j) s += hh[b * 50 + j] * fc2w[k * 50 + j];
    out[b * 2 + k] = s;
  }
}

extern "C" void kernel_launch(void* const* d_in, const int* in_sizes, int n_in,
                              void* d_out, int out_size, void* d_ws, size_t ws_size,
                              hipStream_t stream) {
  (void)in_sizes; (void)n_in; (void)out_size;
  const float* inp  = (const float*)d_in[0];
  const float* W0   = (const float*)d_in[1];
  const float* W1   = (const float*)d_in[2];
  const float* W2   = (const float*)d_in[3];
  const float* fc1w = (const float*)d_in[4];
  const float* fc1b = (const float*)d_in[5];
  const float* fc2w = (const float*)d_in[6];
  const float* fc2b = (const float*)d_in[7];
  float* out = (float*)d_out;

  float* ws = (float*)d_ws;
  float* A0 = ws;                      // 12,545,280
  float* A1 = A0 + (size_t)12545280;   // 2,073,600
  float* S  = A1 + (size_t)2073600;    // 2048 (uses 1920)
  float* Z1 = S + 2048;                // variable

  const size_t favail = ws_size / 4;
  const size_t base = (size_t)12545280 + 2073600 + 2048;  // 14,620,928

  // conv0 fused: inp -> A0 (gated, padded 36). grid 8*73*2 = 1168.
  hipLaunchKernelGGL(conv0_kernel, dim3(1168), dim3(256), 0, stream, inp, W0, A0);

  // conv1 A: z-paired. SPI = 9*18*9 = 1458, NB = 6.
  if (favail >= base + (size_t)16 * 60 * 5832) {
    // full: grid 8*6*20*2 = 1920.
    hipLaunchKernelGGL((convA2_kernel<20, 33, 18, 36, 16>), dim3(1920), dim3(256), 0, stream,
                       A0, Z1, 0);
    hipLaunchKernelGGL((convB_kernel<60, 18, 20, 16>), dim3(729), dim3(128), 0, stream,
                       Z1, W1, A1);
  } else if (favail >= base + (size_t)8 * 60 * 5832) {
    for (int h = 0; h < 2; ++h) {
      hipLaunchKernelGGL((convA2_kernel<20, 33, 18, 36, 8>), dim3(960), dim3(256), 0, stream,
                         A0, Z1, 8 * h);
      hipLaunchKernelGGL((convB_kernel<60, 18, 20, 8>), dim3(365), dim3(128), 0, stream,
                         Z1, W1, A1 + (size_t)8 * h * 20 * 6480);
    }
  } else {
    for (int h = 0; h < 4; ++h) {
      hipLaunchKernelGGL((convA2_kernel<20, 33, 18, 36, 4>), dim3(960), dim3(256), 0, stream,
                         A0, Z1, 4 * h);
      hipLaunchKernelGGL((convB_kernel<60, 18, 20, 4>), dim3(183), dim3(128), 0, stream,
                         Z1, W1, A1 + (size_t)4 * h * 20 * 6480);
    }
  }

  // conv2 phase A + spatial reduce: A1 -> S[16][60][2]. grid 8*2*20*2 = 640.
  hipLaunchKernelGGL((convA_red_kernel<20, 18, 10, 20, 16>), dim3(640), dim3(256), 0, stream,
                     A1, S, 0);
  // conv2 mix (commuted) + fc.
  hipLaunchKernelGGL(fc_kernel, dim3(1), dim3(256), 0, stream, S, W2, fc1w, fc1b, fc2w, fc2b,
                     out);
}

// Round 17
// 83.073 us; speedup vs baseline: 1.5870x; 1.5870x over previous
//
#include <hip/hip_runtime.h>
#include <math.h>
#include <type_traits>

constexpr int BATCH = 16;

// ---------------------------------------------------------------------------
// Round 17: exact revert to the round-15 optimum (82.6 us). Round 16's
// z-paired conv1A regressed 3x: VGPR 136 (static 7-plane unroll + dual z
// state) -> 3 waves/SIMD, and per-plane sched_barrier(0) serialized plane
// loads (MLP cap) — the round-3/6 failure modes combined. The round-15
// structure is the measured local optimum: conv0 fused (z-only hot loop),
// conv1 two-phase, conv2A reduced in-kernel, conv2-mix commuted into fc.
//
// Workspace (floats):
//   A0 [16][20][33][33][36] : 12,545,280  (rows padded ->36)
//   A1 [16][20][18][18][20] :  2,073,600  (rows padded ->20)
//   S  [16][60][2] (pad)    :      2,048
//   Z1 [16][60][5832]       :  5,598,720  (full; half/quarter tiers smaller)
// ---------------------------------------------------------------------------

__host__ __device__ constexpr int QI(int q) {  // q = ay^2+ax^2 in {0,1,2,4,5,8}
  return q == 0 ? 0 : q == 1 ? 1 : q == 2 ? 2 : q == 4 ? 3 : q == 5 ? 4 : 5;
}

// Shared per-block radial-basis synthesis: lbv[40] = B_j value per r^2-class
// (4-padded), normalized analytically via class multiplicities.
__device__ __forceinline__ void synth_basis(float* lbv, float* lnrm, int t) {
  if (t < 40) {
    const int gc = t >> 2, j = t & 3;
    const float R2C[10] = {0.f, 1.f, 2.f, 3.f, 4.f, 5.f, 6.f, 8.f, 9.f, 12.f};
    float raw = 0.f;
    if (j < 3) {
      const float d = (sqrtf(R2C[gc]) - (float)j) * (1.0f / 0.6f);
      raw = expf(-0.5f * d * d);
    }
    lbv[t] = raw;
  }
  __syncthreads();
  if (t < 3) {
    const float MULT[10] = {1.f, 6.f, 12.f, 8.f, 6.f, 24.f, 24.f, 12.f, 24.f, 8.f};
    float ssum = 0.f;
    for (int gc = 0; gc < 10; ++gc) {
      const float v = lbv[gc * 4 + t];
      ssum += MULT[gc] * v * v;
    }
    lnrm[t] = rsqrtf(ssum);
  }
  __syncthreads();
  if (t < 40) lbv[t] = ((t & 3) < 3) ? lbv[t] * lnrm[t & 3] : 0.f;
  __syncthreads();
}

// The radial tap-sum core: computes z[3][2] for a 2-voxel strip of one input
// channel. Shared by all conv kernels.
template <int DIN, int DOUT, int IRS>
__device__ __forceinline__ void radial_z(const float* __restrict__ ipc,
                                         const float* __restrict__ lbv,
                                         int zo, int yo, int xo0,
                                         const bool* xok, const int* yoff,
                                         const bool* yok, int offA, int offB,
                                         float (&z)[3][2]) {
#pragma unroll
  for (int j = 0; j < 3; ++j) { z[j][0] = 0.f; z[j][1] = 0.f; }

  auto plane = [&](auto azc_c, int kz) {
    constexpr int AZC = decltype(azc_c)::value;
    constexpr int GM[3][6] = {
        {0, 1, 2, 4, 5, 7}, {1, 2, 3, 5, 6, 8}, {4, 5, 6, 7, 8, 9}};
    constexpr int A2T[5] = {4, 1, 0, 1, 4};
    const int zi = 2 * zo - 3 + kz;
    const bool zok = (unsigned)zi < (unsigned)DIN;
    const float* pl = ipc + (size_t)min(max(zi, 0), DIN - 1) * (DIN * IRS);
    float4 pa[5], pb[5];
#pragma unroll
    for (int ky = 0; ky < 5; ++ky) {
      const float* row = pl + yoff[ky];
      pa[ky] = *(const float4*)(row + offA);
      pb[ky] = *(const float4*)(row + offB);
    }
    float pq[6][2];
#pragma unroll
    for (int qi = 0; qi < 6; ++qi) { pq[qi][0] = 0.f; pq[qi][1] = 0.f; }
#pragma unroll
    for (int ky = 0; ky < 5; ++ky) {
      float v[7] = {pa[ky].y, pa[ky].z, pa[ky].w, pb[ky].x, pb[ky].y, pb[ky].z, pb[ky].w};
      const bool yz = zok && yok[ky];
#pragma unroll
      for (int p = 0; p < 7; ++p) v[p] = (yz && xok[p]) ? v[p] : 0.f;
#pragma unroll
      for (int kx = 0; kx < 5; ++kx) {
        pq[QI(A2T[ky] + A2T[kx])][0] += v[kx];
        pq[QI(A2T[ky] + A2T[kx])][1] += v[2 + kx];
      }
    }
#pragma unroll
    for (int qi = 0; qi < 6; ++qi) {
      const float4 bv4 = *(const float4*)&lbv[GM[AZC][qi] * 4];
#pragma unroll
      for (int n = 0; n < 2; ++n) {
        z[0][n] = fmaf(bv4.x, pq[qi][n], z[0][n]);
        z[1][n] = fmaf(bv4.y, pq[qi][n], z[1][n]);
        z[2][n] = fmaf(bv4.z, pq[qi][n], z[2][n]);
      }
    }
  };

  plane(std::integral_constant<int, 0>{}, 2);
#pragma unroll 1
  for (int rep = 0; rep < 2; ++rep) plane(std::integral_constant<int, 1>{}, 1 + 2 * rep);
#pragma unroll 1
  for (int rep = 0; rep < 2; ++rep) plane(std::integral_constant<int, 2>{}, 4 * rep);
}

// conv0 fused: ICT=1, so tap-sum -> z[3][2] -> 23x3 mix + gate in epilogue.
// in: [16][64^3] packed, out: A0 [16][20][33][33][36].
__global__ __launch_bounds__(256)
void conv0_kernel(const float* __restrict__ in, const float* __restrict__ W0,
                  float* __restrict__ out) {
  constexpr int DIN = 64, DOUT = 33, IRS = 64, ORS = 36;
  constexpr int ISLAB = DIN * DIN * IRS;
  constexpr int OSLAB = DOUT * DOUT * ORS;
  constexpr int XS = 17, SPI = DOUT * DOUT * XS, NB = (SPI + 255) / 256;

  __shared__ __align__(16) float lbv[40];
  __shared__ float lnrm[4];
  __shared__ __align__(16) float lw[3 * 24];

  const int bid = blockIdx.x;
  const int xcd = bid & 7;
  int slot = bid >> 3;
  const int chunk = slot % NB; slot /= NB;
  const int b = xcd + 8 * slot;  // slot in [0,2)
  const int t = threadIdx.x;

  synth_basis(lbv, lnrm, t);
  if (t < 72) {
    const int oc = t % 24, j = t / 24;
    lw[t] = (oc < 23) ? W0[oc * 3 + j] : 0.f;
  }
  __syncthreads();

  const int s = chunk * 256 + t;
  const bool active = s < SPI;
  const int si = active ? s : 0;
  const int zo = si / (DOUT * XS);
  const int yo = (si / XS) % DOUT;
  const int xo0 = (si % XS) * 2;

  const float* __restrict__ ipc = in + (size_t)b * ISLAB;
  const int offA = max(2 * xo0 - 4, 0);
  const int offB = min(2 * xo0, IRS - 4);
  bool xok[7];
#pragma unroll
  for (int p = 0; p < 7; ++p) xok[p] = (unsigned)(2 * xo0 - 3 + p) < (unsigned)DIN;
  int yoff[5];
  bool yok[5];
#pragma unroll
  for (int ky = 0; ky < 5; ++ky) {
    const int yi = 2 * yo - 3 + ky;
    yok[ky] = (unsigned)yi < (unsigned)DIN;
    yoff[ky] = min(max(yi, 0), DIN - 1) * IRS;
  }

  float z[3][2];
  radial_z<DIN, DOUT, IRS>(ipc, lbv, zo, yo, xo0, xok, yoff, yok, offA, offB, z);

  if (!active) return;
  float* __restrict__ op = out + (size_t)b * 20 * OSLAB + (zo * DOUT + yo) * ORS + xo0;
#pragma unroll
  for (int n = 0; n < 2; ++n) {
    if (xo0 + n < DOUT) {
      float acc[24];
#pragma unroll
      for (int c4 = 0; c4 < 6; ++c4) {
        const float4 w0 = *(const float4*)&lw[0 * 24 + 4 * c4];
        const float4 w1 = *(const float4*)&lw[1 * 24 + 4 * c4];
        const float4 w2 = *(const float4*)&lw[2 * 24 + 4 * c4];
        acc[c4 * 4 + 0] = w0.x * z[0][n] + w1.x * z[1][n] + w2.x * z[2][n];
        acc[c4 * 4 + 1] = w0.y * z[0][n] + w1.y * z[1][n] + w2.y * z[2][n];
        acc[c4 * 4 + 2] = w0.z * z[0][n] + w1.z * z[1][n] + w2.z * z[2][n];
        acc[c4 * 4 + 3] = w0.w * z[0][n] + w1.w * z[1][n] + w2.w * z[2][n];
      }
      const float g0 = 1.f / (1.f + expf(-acc[20]));
      const float g1 = 1.f / (1.f + expf(-acc[21]));
      const float g2 = 1.f / (1.f + expf(-acc[22]));
#pragma unroll
      for (int c = 0; c < 5; ++c) op[(size_t)c * OSLAB + n] = fmaxf(acc[c], 0.f);
#pragma unroll
      for (int c = 0; c < 3; ++c) op[(size_t)(5 + c) * OSLAB + n] = acc[5 + c] * g0;
#pragma unroll
      for (int c = 0; c < 5; ++c) op[(size_t)(8 + c) * OSLAB + n] = acc[8 + c] * g1;
#pragma unroll
      for (int c = 0; c < 7; ++c) op[(size_t)(13 + c) * OSLAB + n] = acc[13 + c] * g2;
    }
  }
}

// conv1/conv2 phase A: z per (ic, 2-voxel strip).
// MODE 0: write Z[brel][ic*3+j][vox]; MODE 1: block-reduce -> S[..][chunk].
template <int ICT, int DIN, int DOUT, int IRS, int MODE, int NBH>
__global__ __launch_bounds__(256)
void convA_kernel(const float* __restrict__ in, float* __restrict__ outp, int bofs) {
  constexpr int ISLAB = DIN * DIN * IRS;
  constexpr int XS = (DOUT + 1) / 2;
  constexpr int SPI = DOUT * DOUT * XS;
  constexpr int NB = (SPI + 255) / 256;
  constexpr int DOUT3 = DOUT * DOUT * DOUT;
  constexpr int XB = (NBH < 8) ? NBH : 8;
  static_assert(MODE == 0 || NB == 2, "S layout assumes 2 chunks");

  __shared__ __align__(16) float lbv[40];
  __shared__ float lnrm[4];
  __shared__ float red[4][3];

  const int bid = blockIdx.x;
  const int xcd = bid & 7;
  int slot = bid >> 3;
  const int chunk = slot % NB; slot /= NB;
  const int ic = slot % ICT;   slot /= ICT;
  const int brel = (xcd % XB) + XB * slot;
  const int b = brel + bofs;
  const int t = threadIdx.x;

  synth_basis(lbv, lnrm, t);

  const int s = chunk * 256 + t;
  const bool active = s < SPI;
  const int si = active ? s : 0;
  const int zo = si / (DOUT * XS);
  const int yo = (si / XS) % DOUT;
  const int xo0 = (si % XS) * 2;

  const float* __restrict__ ipc = in + (size_t)(b * ICT + ic) * ISLAB;
  const int offA = max(2 * xo0 - 4, 0);
  const int offB = min(2 * xo0, IRS - 4);
  bool xok[7];
#pragma unroll
  for (int p = 0; p < 7; ++p) xok[p] = (unsigned)(2 * xo0 - 3 + p) < (unsigned)DIN;
  int yoff[5];
  bool yok[5];
#pragma unroll
  for (int ky = 0; ky < 5; ++ky) {
    const int yi = 2 * yo - 3 + ky;
    yok[ky] = (unsigned)yi < (unsigned)DIN;
    yoff[ky] = min(max(yi, 0), DIN - 1) * IRS;
  }

  float z[3][2];
  radial_z<DIN, DOUT, IRS>(ipc, lbv, zo, yo, xo0, xok, yoff, yok, offA, offB, z);

  if constexpr (MODE == 0) {
    if (!active) return;
    const int vbase = (zo * DOUT + yo) * DOUT + xo0;
    float* __restrict__ zp = outp + ((size_t)(brel * ICT + ic) * 3) * DOUT3 + vbase;
#pragma unroll
    for (int j = 0; j < 3; ++j) {
      zp[(size_t)j * DOUT3] = z[j][0];
      if (xo0 + 1 < DOUT) zp[(size_t)j * DOUT3 + 1] = z[j][1];
    }
  } else {
    float v3[3];
#pragma unroll
    for (int j = 0; j < 3; ++j) v3[j] = active ? (z[j][0] + z[j][1]) : 0.f;
#pragma unroll
    for (int j = 0; j < 3; ++j) {
#pragma unroll
      for (int off = 32; off > 0; off >>= 1) v3[j] += __shfl_down(v3[j], off);
    }
    const int lane = t & 63, wv = t >> 6;
    if (lane == 0) {
#pragma unroll
      for (int j = 0; j < 3; ++j) red[wv][j] = v3[j];
    }
    __syncthreads();
    if (t < 3)
      outp[((size_t)(brel * ICT + ic) * 3 + t) * NB + chunk] =
          (red[0][t] + red[1][t]) + (red[2][t] + red[3][t]);
  }
}

// Phase B: channel mix (23 out-ch from K z-features) + capsule gating.
template <int K, int DOUT, int ORS, int NBH>
__global__ __launch_bounds__(128)
void convB_kernel(const float* __restrict__ Z, const float* __restrict__ W,
                  float* __restrict__ out) {
  constexpr int ICT = K / 3;
  constexpr int DOUT3 = DOUT * DOUT * DOUT;
  constexpr int OSLAB = DOUT * DOUT * ORS;

  __shared__ __align__(16) float lw[K * 24];
  const int t = threadIdx.x;
  for (int i = t; i < K * 24; i += 128) {
    const int oc = i % 24, k = i / 24, icc = k / 3, jj = k % 3;
    lw[i] = (oc < 23) ? W[((size_t)oc * ICT + icc) * 3 + jj] : 0.f;
  }
  __syncthreads();

  const int gv = blockIdx.x * 128 + t;
  if (gv >= NBH * DOUT3) return;
  const int b = gv / DOUT3;
  const int vox = gv % DOUT3;

  float acc[24];
#pragma unroll
  for (int c = 0; c < 24; ++c) acc[c] = 0.f;

  const float* __restrict__ zp = Z + (size_t)b * K * DOUT3 + vox;
#pragma unroll 10
  for (int k = 0; k < K; ++k) {
    const float zv = zp[(size_t)k * DOUT3];
#pragma unroll
    for (int c4 = 0; c4 < 6; ++c4) {
      const float4 w4 = *(const float4*)&lw[k * 24 + 4 * c4];
      acc[c4 * 4 + 0] = fmaf(w4.x, zv, acc[c4 * 4 + 0]);
      acc[c4 * 4 + 1] = fmaf(w4.y, zv, acc[c4 * 4 + 1]);
      acc[c4 * 4 + 2] = fmaf(w4.z, zv, acc[c4 * 4 + 2]);
      acc[c4 * 4 + 3] = fmaf(w4.w, zv, acc[c4 * 4 + 3]);
    }
  }

  const int zz = vox / (DOUT * DOUT), yy = (vox / DOUT) % DOUT, xx = vox % DOUT;
  float* __restrict__ op = out + (size_t)b * 20 * OSLAB + (zz * DOUT + yy) * ORS + xx;
  const float g0 = 1.f / (1.f + expf(-acc[20]));
  const float g1 = 1.f / (1.f + expf(-acc[21]));
  const float g2 = 1.f / (1.f + expf(-acc[22]));
#pragma unroll
  for (int c = 0; c < 5; ++c) op[(size_t)c * OSLAB] = fmaxf(acc[c], 0.f);
#pragma unroll
  for (int c = 0; c < 3; ++c) op[(size_t)(5 + c) * OSLAB] = acc[5 + c] * g0;
#pragma unroll
  for (int c = 0; c < 5; ++c) op[(size_t)(8 + c) * OSLAB] = acc[8 + c] * g1;
#pragma unroll
  for (int c = 0; c < 7; ++c) op[(size_t)(13 + c) * OSLAB] = acc[13 + c] * g2;
}

// conv2 channel-mix (commuted past AvgSpacial) + fc1(relu) + fc2, one block.
__global__ __launch_bounds__(256)
void fc_kernel(const float* __restrict__ S, const float* __restrict__ W2,
               const float* __restrict__ fc1w, const float* __restrict__ fc1b,
               const float* __restrict__ fc2w, const float* __restrict__ fc2b,
               float* __restrict__ out) {
  const int t = threadIdx.x;
  __shared__ float SB[960];
  __shared__ float xs[320];
  __shared__ float hh[800];
  for (int i = t; i < 960; i += 256)
    SB[i] = S[(size_t)i * 2] + S[(size_t)i * 2 + 1];
  __syncthreads();
  for (int i = t; i < 320; i += 256) {
    const int b = i / 20, oc = i % 20;
    float s = 0.f;
    for (int k = 0; k < 60; ++k) s += W2[oc * 60 + k] * SB[b * 60 + k];
    xs[i] = s * (1.0f / 1000.0f);
  }
  __syncthreads();
  for (int i = t; i < 800; i += 256) {
    const int b = i / 50, j = i % 50;
    float s = fc1b[j];
    for (int c = 0; c < 20; ++c) s += xs[b * 20 + c] * fc1w[j * 20 + c];
    hh[i] = fmaxf(s, 0.f);
  }
  __syncthreads();
  for (int i = t; i < 32; i += 256) {
    const int b = i / 2, k = i % 2;
    float s = fc2b[k];
    for (int j = 0; j < 50; ++j) s += hh[b * 50 + j] * fc2w[k * 50 + j];
    out[b * 2 + k] = s;
  }
}

extern "C" void kernel_launch(void* const* d_in, const int* in_sizes, int n_in,
                              void* d_out, int out_size, void* d_ws, size_t ws_size,
                              hipStream_t stream) {
  (void)in_sizes; (void)n_in; (void)out_size;
  const float* inp  = (const float*)d_in[0];
  const float* W0   = (const float*)d_in[1];
  const float* W1   = (const float*)d_in[2];
  const float* W2   = (const float*)d_in[3];
  const float* fc1w = (const float*)d_in[4];
  const float* fc1b = (const float*)d_in[5];
  const float* fc2w = (const float*)d_in[6];
  const float* fc2b = (const float*)d_in[7];
  float* out = (float*)d_out;

  float* ws = (float*)d_ws;
  float* A0 = ws;                      // 12,545,280
  float* A1 = A0 + (size_t)12545280;   // 2,073,600
  float* S  = A1 + (size_t)2073600;    // 2048 (uses 1920)
  float* Z1 = S + 2048;                // variable

  const size_t favail = ws_size / 4;
  const size_t base = (size_t)12545280 + 2073600 + 2048;  // 14,620,928

  // conv0 fused: inp -> A0 (gated, padded 36). grid 8*73*2 = 1168.
  hipLaunchKernelGGL(conv0_kernel, dim3(1168), dim3(256), 0, stream, inp, W0, A0);

  if (favail >= base + (size_t)16 * 60 * 5832) {
    // conv1 A: A0 -> Z1[16][60][5832]. grid 8*12*20*2 = 3840.
    hipLaunchKernelGGL((convA_kernel<20, 33, 18, 36, 0, 16>), dim3(3840), dim3(256), 0, stream,
                       A0, Z1, 0);
    // conv1 B: Z1 -> A1 (gated, padded 20). 16*5832/128 -> 729 blocks.
    hipLaunchKernelGGL((convB_kernel<60, 18, 20, 16>), dim3(729), dim3(128), 0, stream,
                       Z1, W1, A1);
  } else if (favail >= base + (size_t)8 * 60 * 5832) {
    for (int h = 0; h < 2; ++h) {
      hipLaunchKernelGGL((convA_kernel<20, 33, 18, 36, 0, 8>), dim3(1920), dim3(256), 0, stream,
                         A0, Z1, 8 * h);
      hipLaunchKernelGGL((convB_kernel<60, 18, 20, 8>), dim3(365), dim3(128), 0, stream,
                         Z1, W1, A1 + (size_t)8 * h * 20 * 6480);
    }
  } else {
    for (int h = 0; h < 4; ++h) {
      hipLaunchKernelGGL((convA_kernel<20, 33, 18, 36, 0, 4>), dim3(1920), dim3(256), 0, stream,
                         A0, Z1, 4 * h);
      hipLaunchKernelGGL((convB_kernel<60, 18, 20, 4>), dim3(183), dim3(128), 0, stream,
                         Z1, W1, A1 + (size_t)4 * h * 20 * 6480);
    }
  }

  // conv2 phase A + spatial reduce: A1 -> S[16][60][2]. grid 8*2*20*2 = 640.
  hipLaunchKernelGGL((convA_kernel<20, 18, 10, 20, 1, 16>), dim3(640), dim3(256), 0, stream,
                     A1, S, 0);
  // conv2 mix (commuted) + fc.
  hipLaunchKernelGGL(fc_kernel, dim3(1), dim3(256), 0, stream, S, W2, fc1w, fc1b, fc2w, fc2b,
                     out);
}